// Round 1
// 1293.977 us; speedup vs baseline: 1.0295x; 1.0295x over previous
//
#include <hip/hip_runtime.h>
#include <hip/hip_bf16.h>
#include <math.h>

// CrossAttentionFusion on MI355X.
// softmax over one key == 1  =>  mha1(q_in, kv) = kv@Wc.T + bc,
//   Wc = Wo@Wv (fused once), bc = Wo@bv + bo.
// 2 tiny weight-combine GEMMs + 7 bf16-MFMA GEMMs + 3 layernorms.
// R6: GEMM restructured 128x128 -> 256x256 tile (BK=32), 8 waves, 4-buffer
// LDS ring (128 KiB) with depth-3 prefetch and COUNTED vmcnt (never drain
// in main loop) + raw s_barrier. R5 counters showed FFN2 at MfmaUtil 17%,
// HBM 8.8%, 2/3 of cycles idle: the 2-phase vmcnt(0)-drain per 310-cycle
// K-step exposed the cold A-stream latency. 256^2 doubles arithmetic
// intensity (128 FLOP/B) and the counted ring keeps 12 loads/thread in
// flight across tiles. Bank swizzle (XOR k-block with row bits, staged on
// the global-source side, un-XORed on the read side) carried over.

typedef unsigned short u16;
typedef __bf16 bf16_t;
typedef bf16_t bf16x8 __attribute__((ext_vector_type(8)));
typedef float f32x4 __attribute__((ext_vector_type(4)));

#define BROWS 16384   // batch
#define EDIM  768

__device__ __forceinline__ u16 f2bf(float f) {
    union { float f; unsigned u; } v; v.f = f;
    return (u16)((v.u + 0x7FFFu + ((v.u >> 16) & 1u)) >> 16);  // RNE
}
__device__ __forceinline__ float bf2f(u16 h) {
    union { unsigned u; float f; } v; v.u = ((unsigned)h) << 16;
    return v.f;
}
// gelu via x*sigmoid(1.5957691*x + 0.0713548*x^3); exp2/rcp HW instrs.
__device__ __forceinline__ float gelu_f(float x) {
    float t = x * x;
    float p = fmaf(0.102943268f, t, 2.30221895f);   // log2(e) folded in
    float e = __builtin_amdgcn_exp2f(-x * p);
    return x * __builtin_amdgcn_rcpf(1.0f + e);
}

// async global->LDS, 16B/lane. LDS dest is wave-uniform base + lane*16.
__device__ __forceinline__ void gld16(const u16* g, u16* l) {
    __builtin_amdgcn_global_load_lds(
        (__attribute__((address_space(1))) void*)g,
        (__attribute__((address_space(3))) void*)l, 16, 0, 0);
}

// ---- batched f32->bf16 conversion: 8 tensors, one dispatch ----
struct ConvBatch {
    const float *s0, *s1, *s2, *s3, *s4, *s5, *s6, *s7;
    u16 *d0, *d1, *d2, *d3, *d4, *d5, *d6, *d7;
};
#define CB0 2304   // fi_W1 3072*768
#define CB1 2304   // fi_W2
#define CB2 2304   // ft_W1
#define CB3 2304   // ft_W2
#define CB4 1152   // fp_W 768*1536
#define CB5 576    // it_Wo 768*768
#define CB6 576    // ti_Wo
#define CB7 12288  // text 16384*768
#define CONV_BLOCKS (CB0+CB1+CB2+CB3+CB4+CB5+CB6+CB7)

__global__ void __launch_bounds__(256) conv8_k(ConvBatch cb) {
    int b = blockIdx.x;
    const float* s; u16* d;
    if      (b < CB0)          { s = cb.s0; d = cb.d0; }
    else if ((b -= CB0) < CB1) { s = cb.s1; d = cb.d1; }
    else if ((b -= CB1) < CB2) { s = cb.s2; d = cb.d2; }
    else if ((b -= CB2) < CB3) { s = cb.s3; d = cb.d3; }
    else if ((b -= CB3) < CB4) { s = cb.s4; d = cb.d4; }
    else if ((b -= CB4) < CB5) { s = cb.s5; d = cb.d5; }
    else if ((b -= CB5) < CB6) { s = cb.s6; d = cb.d6; }
    else    { b -= CB6;          s = cb.s7; d = cb.d7; }
    int i = b * 256 + threadIdx.x;
    float4 v = ((const float4*)s)[i];
    ushort4 o;
    o.x = f2bf(v.x); o.y = f2bf(v.y); o.z = f2bf(v.z); o.w = f2bf(v.w);
    ((ushort4*)d)[i] = o;
}

// D[c,r] = bf16(S[r,c]) — transpose-convert (Wv.T for the weight combine).
__global__ void __launch_bounds__(256) f32_to_bf16_T_k(const float* __restrict__ S,
                                                       u16* __restrict__ D,
                                                       int R, int C) {
    __shared__ float t[32][33];
    const int r0 = blockIdx.y * 32, c0 = blockIdx.x * 32;
    const int tx = threadIdx.x & 31, ty = threadIdx.x >> 5;  // ty 0..7
#pragma unroll
    for (int i = ty; i < 32; i += 8) t[i][tx] = S[(long)(r0 + i) * C + c0 + tx];
    __syncthreads();
#pragma unroll
    for (int i = ty; i < 32; i += 8) D[(long)(c0 + i) * R + r0 + tx] = f2bf(t[tx][i]);
}

// bc[n] = bo[n] + dot(Wo[n,:], bv)
__global__ void __launch_bounds__(256) bias_comb_k(const float* __restrict__ Wo,
                                                   const float* __restrict__ bv,
                                                   const float* __restrict__ bo,
                                                   float* __restrict__ bc, int K) {
    const int n = blockIdx.x * 4 + (threadIdx.x >> 6);
    const int lane = threadIdx.x & 63;
    float s = 0.f;
    for (int k = lane; k < K; k += 64) s += Wo[(long)n * K + k] * bv[k];
#pragma unroll
    for (int o = 32; o > 0; o >>= 1) s += __shfl_down(s, o, 64);
    if (lane == 0) bc[n] = s + bo[n];
}

// C[m,n] = sum_k A[m,k] * W[n,k]  (+bias, +f32 or bf16 residual, opt gelu)
// 256x256 tile, BK=32, 8 waves (2x4), per-wave C = 128x64.
// LDS: 4-buffer ring (A,B 16KB each per buf = 128 KiB total), depth-3
// prefetch, counted vmcnt. 1 block/CU.
__global__ void __launch_bounds__(512, 2) gemm_bt(
    const u16* __restrict__ A, int lda,
    const u16* __restrict__ W,
    const float* __restrict__ bias,
    const float* __restrict__ R, int ldr,      // f32 residual (or null)
    const u16* __restrict__ Rb, int ldrb,      // bf16 residual (or null)
    float* __restrict__ Cf, int ldcf,
    u16* __restrict__ Cb, int ldcb,
    int K, int do_gelu)
{
    __shared__ alignas(16) u16 sA[4][256 * 32];  // [buf][row*32+k]
    __shared__ alignas(16) u16 sB[4][256 * 32];

    const int tid  = threadIdx.x;
    const int lane = tid & 63;
    const int wave = tid >> 6;     // 0..7
    const int wm = wave >> 2;      // 0..1  (M half)
    const int wn = wave & 3;       // 0..3  (N quarter)

    // XCD-aware swizzle: id%8 = XCD (round-robin dispatch). Give each XCD a
    // contiguous slab of row-tiles; sweep col-tiles fastest within the slab.
    int bm, bn;
    {
        const int gx = gridDim.x, gy = gridDim.y;
        const int id = blockIdx.y * gx + blockIdx.x;
        if ((gy & 7) == 0) {
            const int xcd = id & 7, slot = id >> 3;
            bn = slot % gx;
            bm = (xcd * (gy >> 3)) + slot / gx;
        } else { bm = blockIdx.y; bn = blockIdx.x; }
    }
    const long m0 = (long)bm * 256;
    const long n0 = (long)bn * 256;

    // staging: 512 threads x 16B = 8KB per gld round; each matrix tile is
    // 16KB -> 2 rounds (rows 0..127, 128..255). Wave w stages rows w*16..+15
    // (1KB, lane-contiguous in LDS). Bank swizzle: lane (r,cb) stages global
    // k-block cb^((r>>1)&3) into LDS slot (r,cb); reads un-XOR it. Absolute
    // row = base + wave*16 + r with base in {0,128}: both preserve
    // (row>>1)&3 == (r>>1)&3 since wave*16 and 128 are 0 mod 8.
    const int r   = lane >> 2;      // 0..15 row within 16-row chunk
    const int cb  = lane & 3;       // 16B column block (LDS slot)
    const int cbs = cb ^ ((r >> 1) & 3);   // global k-block staged by lane
    const u16* gA0 = A + (m0 + wave * 16 + r) * (long)lda + cbs * 8;
    const u16* gA1 = gA0 + 128 * (long)lda;
    const u16* gB0 = W + (n0 + wave * 16 + r) * (long)K + cbs * 8;
    const u16* gB1 = gB0 + 128 * (long)K;

    auto stage = [&](int buf, int kt) {     // 4 gld16/thread per tile
        const int kk = kt * 32;
        gld16(gA0 + kk, sA[buf] + wave * 512);
        gld16(gA1 + kk, sA[buf] + 4096 + wave * 512);
        gld16(gB0 + kk, sB[buf] + wave * 512);
        gld16(gB1 + kk, sB[buf] + 4096 + wave * 512);
    };

    const int quad = lane >> 4;    // 0..3 -> k = quad*8 + j
    const int l16  = lane & 15;    // m (A) / n (B) index
    int offA[8], offB[4];
#pragma unroll
    for (int t = 0; t < 8; t++) {
        const int rowA = wm * 128 + t * 16 + l16;
        offA[t] = rowA * 32 + (quad ^ ((rowA >> 1) & 3)) * 8;
    }
#pragma unroll
    for (int t = 0; t < 4; t++) {
        const int rowB = wn * 64 + t * 16 + l16;
        offB[t] = rowB * 32 + (quad ^ ((rowB >> 1) & 3)) * 8;
    }

    f32x4 acc[8][4];
#pragma unroll
    for (int i = 0; i < 8; i++)
#pragma unroll
        for (int j = 0; j < 4; j++) {
            f32x4 z = {0.f, 0.f, 0.f, 0.f};
            acc[i][j] = z;
        }

    const int nt = K >> 5;         // K-tiles of 32
    // prologue: fill the ring 3 deep (12 loads/thread in flight)
    if (nt > 0) stage(0, 0);
    if (nt > 1) stage(1, 1);
    if (nt > 2) stage(2, 2);

    for (int t = 0; t < nt; ++t) {
        if (t + 3 < nt) stage((t + 3) & 3, t + 3);   // keep ring 3 deep
        // counted wait: tiles t+1..min(t+3,nt-1) stay in flight (4 loads
        // each, FIFO completion) — tile t is guaranteed landed, stream
        // never drains to zero in steady state.
        const int fl = nt - 1 - t;
        if (fl >= 3)      asm volatile("s_waitcnt vmcnt(12)" ::: "memory");
        else if (fl == 2) asm volatile("s_waitcnt vmcnt(8)"  ::: "memory");
        else if (fl == 1) asm volatile("s_waitcnt vmcnt(4)"  ::: "memory");
        else              asm volatile("s_waitcnt vmcnt(0)"  ::: "memory");
        __builtin_amdgcn_s_barrier();          // all waves' tile-t landed
        asm volatile("" ::: "memory");
        const u16* pA = sA[t & 3];
        const u16* pB = sB[t & 3];
        bf16x8 af[8], bfr[4];
#pragma unroll
        for (int i = 0; i < 8; i++) af[i]  = *(const bf16x8*)(pA + offA[i]);
#pragma unroll
        for (int i = 0; i < 4; i++) bfr[i] = *(const bf16x8*)(pB + offB[i]);
        __builtin_amdgcn_s_setprio(1);
#pragma unroll
        for (int mt = 0; mt < 8; mt++)
#pragma unroll
            for (int nb = 0; nb < 4; nb++)
                acc[mt][nb] = __builtin_amdgcn_mfma_f32_16x16x32_bf16(
                    af[mt], bfr[nb], acc[mt][nb], 0, 0, 0);
        __builtin_amdgcn_s_setprio(0);
        asm volatile("" ::: "memory");
        __builtin_amdgcn_s_barrier();          // reads done before buf reuse
        asm volatile("" ::: "memory");
    }

    // epilogue: C/D layout col = lane&15, row = quad*4 + reg  [m89/m91]
#pragma unroll
    for (int mt = 0; mt < 8; mt++) {
#pragma unroll
        for (int nb = 0; nb < 4; nb++) {
            const long col = n0 + wn * 64 + nb * 16 + l16;
            const float bv = bias ? bias[col] : 0.0f;
#pragma unroll
            for (int rr = 0; rr < 4; rr++) {
                const long row = m0 + wm * 128 + mt * 16 + quad * 4 + rr;
                float v = acc[mt][nb][rr] + bv;
                if (R)  v += R[row * (long)ldr + col];
                if (Rb) v += bf2f(Rb[row * (long)ldrb + col]);
                if (do_gelu) v = gelu_f(v);
                if (Cf) Cf[row * (long)ldcf + col] = v;
                if (Cb) Cb[row * (long)ldcb + col] = f2bf(v);
            }
        }
    }
}

// LayerNorm over 768 cols, one block/row. Input bf16 (Xb) or f32 (Xf);
// output f32 (Yf) and/or bf16 (Yb); optional gelu. 192 active lanes x 4 elems.
__global__ void __launch_bounds__(256) ln_k(
    const u16*  __restrict__ Xb,
    const float* __restrict__ Xf,
    const float* __restrict__ g,
    const float* __restrict__ b,
    float* __restrict__ Yf,
    u16*   __restrict__ Yb,
    int do_gelu)
{
    const int row = blockIdx.x;
    const int tid = threadIdx.x;
    float v[4] = {0.f, 0.f, 0.f, 0.f};
    if (tid < 192) {
        if (Xb) {
            ushort4 u = ((const ushort4*)(Xb + (long)row * EDIM))[tid];
            v[0] = bf2f(u.x); v[1] = bf2f(u.y); v[2] = bf2f(u.z); v[3] = bf2f(u.w);
        } else {
            float4 f = ((const float4*)(Xf + (long)row * EDIM))[tid];
            v[0] = f.x; v[1] = f.y; v[2] = f.z; v[3] = f.w;
        }
    }
    float s = 0.f, s2 = 0.f;
#pragma unroll
    for (int j = 0; j < 4; j++) { s += v[j]; s2 += v[j] * v[j]; }
#pragma unroll
    for (int o = 32; o > 0; o >>= 1) {
        s  += __shfl_down(s,  o, 64);
        s2 += __shfl_down(s2, o, 64);
    }
    __shared__ float red[8];
    __shared__ float mb[2];
    const int wave = tid >> 6, lane = tid & 63;
    if (lane == 0) { red[wave] = s; red[4 + wave] = s2; }
    __syncthreads();
    if (tid == 0) {
        float S  = red[0] + red[1] + red[2] + red[3];
        float S2 = red[4] + red[5] + red[6] + red[7];
        float mean = S * (1.0f / 768.0f);
        float var  = S2 * (1.0f / 768.0f) - mean * mean;
        mb[0] = mean;
        mb[1] = rsqrtf(var + 1e-5f);
    }
    __syncthreads();
    if (tid < 192) {
        const float mean = mb[0], inv = mb[1];
        float y[4];
#pragma unroll
        for (int j = 0; j < 4; j++) {
            const int c = tid * 4 + j;
            y[j] = (v[j] - mean) * inv * g[c] + b[c];
            if (do_gelu) y[j] = gelu_f(y[j]);
        }
        if (Yf) {
            float4 o = {y[0], y[1], y[2], y[3]};
            ((float4*)(Yf + (long)row * EDIM))[tid] = o;
        }
        if (Yb) {
            ushort4 o = {f2bf(y[0]), f2bf(y[1]), f2bf(y[2]), f2bf(y[3])};
            ((ushort4*)(Yb + (long)row * EDIM))[tid] = o;
        }
    }
}

extern "C" void kernel_launch(void* const* d_in, const int* in_sizes, int n_in,
                              void* d_out, int out_size, void* d_ws, size_t ws_size,
                              hipStream_t stream) {
    (void)in_sizes; (void)n_in; (void)out_size;
    const float* image    = (const float*)d_in[0];
    const float* text     = (const float*)d_in[1];
    const float* it_Wv    = (const float*)d_in[4];
    const float* it_Wo    = (const float*)d_in[5];
    const float* it_bv    = (const float*)d_in[8];
    const float* it_bo    = (const float*)d_in[9];
    const float* ti_Wv    = (const float*)d_in[12];
    const float* ti_Wo    = (const float*)d_in[13];
    const float* ti_bv    = (const float*)d_in[16];
    const float* ti_bo    = (const float*)d_in[17];
    const float* ln_img_g = (const float*)d_in[18];
    const float* ln_img_b = (const float*)d_in[19];
    const float* ln_txt_g = (const float*)d_in[20];
    const float* ln_txt_b = (const float*)d_in[21];
    const float* fp_ln_g  = (const float*)d_in[22];
    const float* fp_ln_b  = (const float*)d_in[23];
    const float* fi_W1    = (const float*)d_in[24];
    const float* fi_b1    = (const float*)d_in[25];
    const float* fi_W2    = (const float*)d_in[26];
    const float* fi_b2    = (const float*)d_in[27];
    const float* ft_W1    = (const float*)d_in[28];
    const float* ft_b1    = (const float*)d_in[29];
    const float* ft_W2    = (const float*)d_in[30];
    const float* ft_b2    = (const float*)d_in[31];
    const float* fp_W     = (const float*)d_in[32];
    const float* fp_b     = (const float*)d_in[33];

    char* ws = (char*)d_ws;
    size_t off = 0;
    auto alloc = [&](size_t bytes) {
        char* p = ws + off; off += (bytes + 255) & ~(size_t)255; return p;
    };
    // bf16 weights (~28 MB, live whole call)
    u16* wo_it = (u16*)alloc((size_t)768 * 768 * 2);
    u16* wvT_it= (u16*)alloc((size_t)768 * 768 * 2);
    u16* wc_it = (u16*)alloc((size_t)768 * 768 * 2);
    u16* wo_ti = (u16*)alloc((size_t)768 * 768 * 2);
    u16* wvT_ti= (u16*)alloc((size_t)768 * 768 * 2);
    u16* wc_ti = (u16*)alloc((size_t)768 * 768 * 2);
    u16* w1i   = (u16*)alloc((size_t)3072 * 768 * 2);
    u16* w2i   = (u16*)alloc((size_t)768 * 3072 * 2);
    u16* w1t   = (u16*)alloc((size_t)3072 * 768 * 2);
    u16* w2t   = (u16*)alloc((size_t)768 * 3072 * 2);
    u16* wp    = (u16*)alloc((size_t)768 * 1536 * 2);
    float* bc_it = (float*)alloc(768 * 4);
    float* bc_ti = (float*)alloc(768 * 4);
    // activations
    u16* vbuf  = (u16*)alloc((size_t)BROWS * 768 * 2);   // post-LN bf16
    u16* fused = (u16*)alloc((size_t)BROWS * 1536 * 2);  // [img | txt] bf16
    u16* text_bf = fused;     // alias: text_bf dead before fused is written
    // hbuf (FFN hidden, adaptive chunk) and pbuf (bf16 pre-LN) share a region.
    int fch = 16384;
    while (fch > 2048 && off + (size_t)fch * 3072 * 2 > ws_size) fch >>= 1;
    size_t region = (size_t)fch * 3072 * 2;
    if (region < (size_t)BROWS * 768 * 2) region = (size_t)BROWS * 768 * 2;
    u16* hbuf = (u16*)alloc(region);
    u16* pbuf = hbuf;

    auto gemm = [&](const u16* A, int lda, const u16* W, int M, int N, int K,
                    const float* bias, const float* R, int ldr,
                    const u16* Rb, int ldrb,
                    float* Cf, int ldcf, u16* Cb, int ldcb, int dg) {
        gemm_bt<<<dim3(N / 256, M / 256), dim3(512), 0, stream>>>(
            A, lda, W, bias, R, ldr, Rb, ldrb, Cf, ldcf, Cb, ldcb, K, dg);
    };
    auto ffn = [&](const u16* xin, const u16* W1, const float* b1,
                   const u16* W2, const float* b2, u16* outp, int ldout) {
        for (int c = 0; c < BROWS / fch; c++) {
            const u16* xc = xin + (size_t)c * fch * 768;
            gemm(xc, 768, W1, fch, 3072, 768, b1,
                 nullptr, 0, nullptr, 0, nullptr, 0, hbuf, 3072, 1);
            gemm(hbuf, 3072, W2, fch, 768, 3072, b2,
                 nullptr, 0, xc, 768,
                 nullptr, 0, outp + (size_t)c * fch * ldout, ldout, 0);
        }
    };

    // ---- conversions: one batched dispatch ----
    ConvBatch cbt = { fi_W1, fi_W2, ft_W1, ft_W2, fp_W, it_Wo, ti_Wo, text,
                      w1i,   w2i,   w1t,   w2t,   wp,   wo_it, wo_ti, text_bf };
    conv8_k<<<dim3(CONV_BLOCKS), dim3(256), 0, stream>>>(cbt);
    // ---- weight combine: Wc = Wo@Wv (bf16), bc = Wo@bv + bo ----
    f32_to_bf16_T_k<<<dim3(24, 24), dim3(256), 0, stream>>>(it_Wv, wvT_it, 768, 768);
    gemm(wo_it, 768, wvT_it, 768, 768, 768, nullptr,
         nullptr, 0, nullptr, 0, nullptr, 0, wc_it, 768, 0);
    bias_comb_k<<<dim3(192), dim3(256), 0, stream>>>(it_Wo, it_bv, it_bo, bc_it, 768);
    f32_to_bf16_T_k<<<dim3(24, 24), dim3(256), 0, stream>>>(ti_Wv, wvT_ti, 768, 768);
    gemm(wo_ti, 768, wvT_ti, 768, 768, 768, nullptr,
         nullptr, 0, nullptr, 0, nullptr, 0, wc_ti, 768, 0);
    bias_comb_k<<<dim3(192), dim3(256), 0, stream>>>(ti_Wo, ti_bv, ti_bo, bc_ti, 768);

    // ---- image path: att = text@Wc.T + bc + image ; LN1 ----
    gemm(text_bf, 768, wc_it, BROWS, 768, 768, bc_it,
         image, 768, nullptr, 0, nullptr, 0, pbuf, 768, 0);
    ln_k<<<dim3(BROWS), dim3(256), 0, stream>>>(
        pbuf, nullptr, ln_img_g, ln_img_b, nullptr, vbuf, 0);
    ffn(vbuf, w1i, fi_b1, w2i, fi_b2, fused, 1536);   // -> fused[:, :768]
    // ---- text path: kv = post-FFN img (fused left half) ----
    gemm(fused, 1536, wc_ti, BROWS, 768, 768, bc_ti,
         text, 768, nullptr, 0, nullptr, 0, pbuf, 768, 0);
    ln_k<<<dim3(BROWS), dim3(256), 0, stream>>>(
        pbuf, nullptr, ln_txt_g, ln_txt_b, nullptr, vbuf, 0);
    ffn(vbuf, w1t, ft_b1, w2t, ft_b2, fused + 768, 1536);  // -> fused[:, 768:]
    // ---- final projection + LN + gelu ----
    gemm(fused, 1536, wp, BROWS, 768, 1536, fp_b,
         nullptr, 0, nullptr, 0, nullptr, 0, pbuf, 768, 0);
    ln_k<<<dim3(BROWS), dim3(256), 0, stream>>>(
        pbuf, nullptr, fp_ln_g, fp_ln_b, (float*)d_out, nullptr, 1);
}

// Round 2
// 1131.767 us; speedup vs baseline: 1.1771x; 1.1433x over previous
//
#include <hip/hip_runtime.h>
#include <hip/hip_bf16.h>
#include <math.h>

// CrossAttentionFusion on MI355X.
// softmax over one key == 1  =>  mha1(q_in, kv) = kv@Wc.T + bc,
//   Wc = Wo@Wv (fused once), bc = Wo@bv + bo.
// 2 tiny weight-combine GEMMs + 7 bf16-MFMA GEMMs + 3 layernorms.
// R7: 8-phase pipelined 256x256 GEMM (m201-style). R6's monolithic
// read->MFMA lockstep left 2/3 of cycles idle (5100 cy/iter vs 1244 ideal).
// Now: K-tile=64, 2 tiles/iter, 8 phases each {4-8 ds_read_b128 | stage one
// 16KB half (2 gld16) | barrier | 16 MFMA @setprio(1) | barrier}; LDS = 4
// k-half slots x 16KB per tensor (128 KiB); counted vmcnt(4) ONLY before the
// mid-barrier of phases 2 and 6 (loads ride 8-12 deep across barriers, never
// drained in-loop; tail stages wrap to keep counts uniform). Hazards checked:
// every stage targets a slot whose last reader finished >=1 barrier earlier;
// each vmcnt lands exactly the 4 halves the next 4 phases read.

typedef unsigned short u16;
typedef __bf16 bf16_t;
typedef bf16_t bf16x8 __attribute__((ext_vector_type(8)));
typedef float f32x4 __attribute__((ext_vector_type(4)));

#define BROWS 16384   // batch
#define EDIM  768

__device__ __forceinline__ u16 f2bf(float f) {
    union { float f; unsigned u; } v; v.f = f;
    return (u16)((v.u + 0x7FFFu + ((v.u >> 16) & 1u)) >> 16);  // RNE
}
__device__ __forceinline__ float bf2f(u16 h) {
    union { unsigned u; float f; } v; v.u = ((unsigned)h) << 16;
    return v.f;
}
// gelu via x*sigmoid(1.5957691*x + 0.0713548*x^3); exp2/rcp HW instrs.
__device__ __forceinline__ float gelu_f(float x) {
    float t = x * x;
    float p = fmaf(0.102943268f, t, 2.30221895f);   // log2(e) folded in
    float e = __builtin_amdgcn_exp2f(-x * p);
    return x * __builtin_amdgcn_rcpf(1.0f + e);
}

// async global->LDS, 16B/lane. LDS dest is wave-uniform base + lane*16.
__device__ __forceinline__ void gld16(const u16* g, u16* l) {
    __builtin_amdgcn_global_load_lds(
        (__attribute__((address_space(1))) void*)g,
        (__attribute__((address_space(3))) void*)l, 16, 0, 0);
}

// ---- batched f32->bf16 conversion: 8 tensors, one dispatch ----
struct ConvBatch {
    const float *s0, *s1, *s2, *s3, *s4, *s5, *s6, *s7;
    u16 *d0, *d1, *d2, *d3, *d4, *d5, *d6, *d7;
};
#define CB0 2304   // fi_W1 3072*768
#define CB1 2304   // fi_W2
#define CB2 2304   // ft_W1
#define CB3 2304   // ft_W2
#define CB4 1152   // fp_W 768*1536
#define CB5 576    // it_Wo 768*768
#define CB6 576    // ti_Wo
#define CB7 12288  // text 16384*768
#define CONV_BLOCKS (CB0+CB1+CB2+CB3+CB4+CB5+CB6+CB7)

__global__ void __launch_bounds__(256) conv8_k(ConvBatch cb) {
    int b = blockIdx.x;
    const float* s; u16* d;
    if      (b < CB0)          { s = cb.s0; d = cb.d0; }
    else if ((b -= CB0) < CB1) { s = cb.s1; d = cb.d1; }
    else if ((b -= CB1) < CB2) { s = cb.s2; d = cb.d2; }
    else if ((b -= CB2) < CB3) { s = cb.s3; d = cb.d3; }
    else if ((b -= CB3) < CB4) { s = cb.s4; d = cb.d4; }
    else if ((b -= CB4) < CB5) { s = cb.s5; d = cb.d5; }
    else if ((b -= CB5) < CB6) { s = cb.s6; d = cb.d6; }
    else    { b -= CB6;          s = cb.s7; d = cb.d7; }
    int i = b * 256 + threadIdx.x;
    float4 v = ((const float4*)s)[i];
    ushort4 o;
    o.x = f2bf(v.x); o.y = f2bf(v.y); o.z = f2bf(v.z); o.w = f2bf(v.w);
    ((ushort4*)d)[i] = o;
}

// D[c,r] = bf16(S[r,c]) — transpose-convert (Wv.T for the weight combine).
__global__ void __launch_bounds__(256) f32_to_bf16_T_k(const float* __restrict__ S,
                                                       u16* __restrict__ D,
                                                       int R, int C) {
    __shared__ float t[32][33];
    const int r0 = blockIdx.y * 32, c0 = blockIdx.x * 32;
    const int tx = threadIdx.x & 31, ty = threadIdx.x >> 5;  // ty 0..7
#pragma unroll
    for (int i = ty; i < 32; i += 8) t[i][tx] = S[(long)(r0 + i) * C + c0 + tx];
    __syncthreads();
#pragma unroll
    for (int i = ty; i < 32; i += 8) D[(long)(c0 + i) * R + r0 + tx] = f2bf(t[tx][i]);
}

// bc[n] = bo[n] + dot(Wo[n,:], bv)
__global__ void __launch_bounds__(256) bias_comb_k(const float* __restrict__ Wo,
                                                   const float* __restrict__ bv,
                                                   const float* __restrict__ bo,
                                                   float* __restrict__ bc, int K) {
    const int n = blockIdx.x * 4 + (threadIdx.x >> 6);
    const int lane = threadIdx.x & 63;
    float s = 0.f;
    for (int k = lane; k < K; k += 64) s += Wo[(long)n * K + k] * bv[k];
#pragma unroll
    for (int o = 32; o > 0; o >>= 1) s += __shfl_down(s, o, 64);
    if (lane == 0) bc[n] = s + bo[n];
}

// C[m,n] = sum_k A[m,k] * W[n,k]  (+bias, +f32 or bf16 residual, opt gelu)
// 256x256 tile, 8 waves (2M x 4N), per-wave C = 128x64. 8-phase pipeline.
__global__ void __launch_bounds__(512, 2) gemm_bt(
    const u16* __restrict__ A, int lda,
    const u16* __restrict__ W,
    const float* __restrict__ bias,
    const float* __restrict__ R, int ldr,      // f32 residual (or null)
    const u16* __restrict__ Rb, int ldrb,      // bf16 residual (or null)
    float* __restrict__ Cf, int ldcf,
    u16* __restrict__ Cb, int ldcb,
    int K, int do_gelu)
{
    // 4 slots per tensor, each = one k-half: 256 rows x 32 k = 16 KB.
    // Tile t: ks-half -> slot (2t+ks)&3. Even tile -> slots 0/1, odd -> 2/3.
    __shared__ alignas(16) u16 sA[4][256 * 32];
    __shared__ alignas(16) u16 sB[4][256 * 32];

    const int tid  = threadIdx.x;
    const int lane = tid & 63;
    const int wave = tid >> 6;     // 0..7
    const int wm = wave >> 2;      // 0..1  (M half)
    const int wn = wave & 3;       // 0..3  (N quarter)

    // XCD-aware swizzle: id%8 = XCD (round-robin dispatch). Give each XCD a
    // contiguous slab of row-tiles; sweep col-tiles fastest within the slab.
    int bm, bn;
    {
        const int gx = gridDim.x, gy = gridDim.y;
        const int id = blockIdx.y * gx + blockIdx.x;
        if ((gy & 7) == 0) {
            const int xcd = id & 7, slot = id >> 3;
            bn = slot % gx;
            bm = (xcd * (gy >> 3)) + slot / gx;
        } else { bm = blockIdx.y; bn = blockIdx.x; }
    }
    const long m0 = (long)bm * 256;
    const long n0 = (long)bn * 256;

    // Staging: one 16KB half per phase = 2 rounds x (512 thr x 16B).
    // Lane l of wave w covers LDS row (rd*128 + w*16 + (l>>2)), 16B-block
    // (l&3); LDS offset = rd*8192 + w*1024 + l*16 (linear per wave ✓ DMA).
    // Bank swizzle: LDS block b of row r holds global k-block b^((r>>1)&3)
    // -> source k-block = (l&3) ^ ((l>>3)&3). Reads un-XOR it.
    const int srow = lane >> 2;                          // 0..15
    const int sk   = ((lane & 3) ^ ((lane >> 3) & 3)) * 8;
    const u16* gA = A + (m0 + wave * 16 + srow) * (long)lda + sk;
    const u16* gB = W + (n0 + wave * 16 + srow) * (long)K + sk;
    const long rdA2 = 128 * (long)lda;
    const long rdB2 = 128 * (long)K;

#define STA(sl, t, ks) do { const u16* g_ = gA + (t) * 64 + (ks) * 32; \
    gld16(g_,        &sA[sl][wave * 512]); \
    gld16(g_ + rdA2, &sA[sl][4096 + wave * 512]); } while (0)
#define STB(sl, t, ks) do { const u16* g_ = gB + (t) * 64 + (ks) * 32; \
    gld16(g_,        &sB[sl][wave * 512]); \
    gld16(g_ + rdB2, &sB[sl][4096 + wave * 512]); } while (0)

    const int quad = lane >> 4;    // 0..3 -> k = quad*8 + j
    const int l16  = lane & 15;    // m (A) / n (B) index within fragment
    const int koff = (quad ^ ((l16 >> 1) & 3)) << 4;     // un-swizzled 16B blk
    const char* baseA = (const char*)&sA[0][0] + wm * 8192 + l16 * 64 + koff;
    const char* baseB = (const char*)&sB[0][0] + wn * 4096 + l16 * 64 + koff;

    f32x4 acc[8][4];
#pragma unroll
    for (int i = 0; i < 8; i++)
#pragma unroll
        for (int j = 0; j < 4; j++) {
            f32x4 z = {0.f, 0.f, 0.f, 0.f};
            acc[i][j] = z;
        }
    bf16x8 af[4], bf[4];

#define FENCE asm volatile("" ::: "memory")
#define BAR   do { FENCE; __builtin_amdgcn_s_barrier(); FENCE; } while (0)
#define VM4   asm volatile("s_waitcnt vmcnt(4)" ::: "memory")
#define NOWAIT ((void)0)

    // Phase: read A-quadrant (4x b128) [+ B k-half (4x b128)], issue one
    // half-tile stage, optional counted vmcnt, barrier, 16 MFMA, barrier.
#define PHASE(SLA, MQ, LB, SLB, STG, WAIT) do {                              \
    _Pragma("unroll")                                                        \
    for (int mf = 0; mf < 4; mf++)                                           \
        af[mf] = *(const bf16x8*)(baseA + (SLA) * 16384 + (MQ) * 4096        \
                                  + mf * 1024);                              \
    if (LB) {                                                                \
        _Pragma("unroll")                                                    \
        for (int nf = 0; nf < 4; nf++)                                       \
            bf[nf] = *(const bf16x8*)(baseB + (SLB) * 16384 + nf * 1024);    \
    }                                                                        \
    STG;                                                                     \
    WAIT;                                                                    \
    BAR;                                                                     \
    __builtin_amdgcn_s_setprio(1);                                           \
    _Pragma("unroll")                                                        \
    for (int mf = 0; mf < 4; mf++)                                           \
        _Pragma("unroll")                                                    \
        for (int nf = 0; nf < 4; nf++)                                       \
            acc[(MQ) * 4 + mf][nf] = __builtin_amdgcn_mfma_f32_16x16x32_bf16(\
                af[mf], bf[nf], acc[(MQ) * 4 + mf][nf], 0, 0, 0);            \
    __builtin_amdgcn_s_setprio(0);                                           \
    BAR;                                                                     \
  } while (0)

    const int nt = K >> 6;         // 64-wide K-tiles; all K here: nt even >= 12
    // Prologue: tile0 fully + tile1 ks0 (6 halves, 12 loads); land tile0.
    STA(0, 0, 0); STB(0, 0, 0);
    STA(1, 0, 1); STB(1, 0, 1);
    STA(2, 1, 0); STB(2, 1, 0);
    VM4;                           // tile0's 8 loads landed, 4 in flight
    BAR;

    for (int T = 0; T < nt; T += 2) {
        const int t2 = (T + 2 < nt) ? T + 2 : 0;   // tail: wrap-stage (never
        const int t3 = (T + 3 < nt) ? T + 3 : 1;   // read; keeps vmcnt uniform)
        PHASE(0, 0, 1, 0, STA(3, T + 1, 1), NOWAIT);   // tile T  ks0, mq0
        PHASE(0, 1, 0, 0, STB(3, T + 1, 1), VM4);      // tile T  ks0, mq1
        PHASE(1, 0, 1, 1, STA(0, t2, 0),    NOWAIT);   // tile T  ks1, mq0
        PHASE(1, 1, 0, 1, STB(0, t2, 0),    NOWAIT);   // tile T  ks1, mq1
        PHASE(2, 0, 1, 2, STA(1, t2, 1),    NOWAIT);   // tile T+1 ks0, mq0
        PHASE(2, 1, 0, 2, STB(1, t2, 1),    VM4);      // tile T+1 ks0, mq1
        PHASE(3, 0, 1, 3, STA(2, t3, 0),    NOWAIT);   // tile T+1 ks1, mq0
        PHASE(3, 1, 0, 3, STB(2, t3, 0),    NOWAIT);   // tile T+1 ks1, mq1
    }

    // epilogue: C/D layout col = lane&15, row = quad*4 + reg  [m89/m91]
#pragma unroll
    for (int mt = 0; mt < 8; mt++) {
#pragma unroll
        for (int nf = 0; nf < 4; nf++) {
            const long col = n0 + wn * 64 + nf * 16 + l16;
            const float bv = bias ? bias[col] : 0.0f;
#pragma unroll
            for (int rr = 0; rr < 4; rr++) {
                const long row = m0 + wm * 128 + mt * 16 + quad * 4 + rr;
                float v = acc[mt][nf][rr] + bv;
                if (R)  v += R[row * (long)ldr + col];
                if (Rb) v += bf2f(Rb[row * (long)ldrb + col]);
                if (do_gelu) v = gelu_f(v);
                if (Cf) Cf[row * (long)ldcf + col] = v;
                if (Cb) Cb[row * (long)ldcb + col] = f2bf(v);
            }
        }
    }
#undef PHASE
#undef STA
#undef STB
#undef VM4
#undef NOWAIT
#undef BAR
#undef FENCE
}

// LayerNorm over 768 cols, one block/row. Input bf16 (Xb) or f32 (Xf);
// output f32 (Yf) and/or bf16 (Yb); optional gelu. 192 active lanes x 4 elems.
__global__ void __launch_bounds__(256) ln_k(
    const u16*  __restrict__ Xb,
    const float* __restrict__ Xf,
    const float* __restrict__ g,
    const float* __restrict__ b,
    float* __restrict__ Yf,
    u16*   __restrict__ Yb,
    int do_gelu)
{
    const int row = blockIdx.x;
    const int tid = threadIdx.x;
    float v[4] = {0.f, 0.f, 0.f, 0.f};
    if (tid < 192) {
        if (Xb) {
            ushort4 u = ((const ushort4*)(Xb + (long)row * EDIM))[tid];
            v[0] = bf2f(u.x); v[1] = bf2f(u.y); v[2] = bf2f(u.z); v[3] = bf2f(u.w);
        } else {
            float4 f = ((const float4*)(Xf + (long)row * EDIM))[tid];
            v[0] = f.x; v[1] = f.y; v[2] = f.z; v[3] = f.w;
        }
    }
    float s = 0.f, s2 = 0.f;
#pragma unroll
    for (int j = 0; j < 4; j++) { s += v[j]; s2 += v[j] * v[j]; }
#pragma unroll
    for (int o = 32; o > 0; o >>= 1) {
        s  += __shfl_down(s,  o, 64);
        s2 += __shfl_down(s2, o, 64);
    }
    __shared__ float red[8];
    __shared__ float mb[2];
    const int wave = tid >> 6, lane = tid & 63;
    if (lane == 0) { red[wave] = s; red[4 + wave] = s2; }
    __syncthreads();
    if (tid == 0) {
        float S  = red[0] + red[1] + red[2] + red[3];
        float S2 = red[4] + red[5] + red[6] + red[7];
        float mean = S * (1.0f / 768.0f);
        float var  = S2 * (1.0f / 768.0f) - mean * mean;
        mb[0] = mean;
        mb[1] = rsqrtf(var + 1e-5f);
    }
    __syncthreads();
    if (tid < 192) {
        const float mean = mb[0], inv = mb[1];
        float y[4];
#pragma unroll
        for (int j = 0; j < 4; j++) {
            const int c = tid * 4 + j;
            y[j] = (v[j] - mean) * inv * g[c] + b[c];
            if (do_gelu) y[j] = gelu_f(y[j]);
        }
        if (Yf) {
            float4 o = {y[0], y[1], y[2], y[3]};
            ((float4*)(Yf + (long)row * EDIM))[tid] = o;
        }
        if (Yb) {
            ushort4 o = {f2bf(y[0]), f2bf(y[1]), f2bf(y[2]), f2bf(y[3])};
            ((ushort4*)(Yb + (long)row * EDIM))[tid] = o;
        }
    }
}

extern "C" void kernel_launch(void* const* d_in, const int* in_sizes, int n_in,
                              void* d_out, int out_size, void* d_ws, size_t ws_size,
                              hipStream_t stream) {
    (void)in_sizes; (void)n_in; (void)out_size;
    const float* image    = (const float*)d_in[0];
    const float* text     = (const float*)d_in[1];
    const float* it_Wv    = (const float*)d_in[4];
    const float* it_Wo    = (const float*)d_in[5];
    const float* it_bv    = (const float*)d_in[8];
    const float* it_bo    = (const float*)d_in[9];
    const float* ti_Wv    = (const float*)d_in[12];
    const float* ti_Wo    = (const float*)d_in[13];
    const float* ti_bv    = (const float*)d_in[16];
    const float* ti_bo    = (const float*)d_in[17];
    const float* ln_img_g = (const float*)d_in[18];
    const float* ln_img_b = (const float*)d_in[19];
    const float* ln_txt_g = (const float*)d_in[20];
    const float* ln_txt_b = (const float*)d_in[21];
    const float* fp_ln_g  = (const float*)d_in[22];
    const float* fp_ln_b  = (const float*)d_in[23];
    const float* fi_W1    = (const float*)d_in[24];
    const float* fi_b1    = (const float*)d_in[25];
    const float* fi_W2    = (const float*)d_in[26];
    const float* fi_b2    = (const float*)d_in[27];
    const float* ft_W1    = (const float*)d_in[28];
    const float* ft_b1    = (const float*)d_in[29];
    const float* ft_W2    = (const float*)d_in[30];
    const float* ft_b2    = (const float*)d_in[31];
    const float* fp_W     = (const float*)d_in[32];
    const float* fp_b     = (const float*)d_in[33];

    char* ws = (char*)d_ws;
    size_t off = 0;
    auto alloc = [&](size_t bytes) {
        char* p = ws + off; off += (bytes + 255) & ~(size_t)255; return p;
    };
    // bf16 weights (~28 MB, live whole call)
    u16* wo_it = (u16*)alloc((size_t)768 * 768 * 2);
    u16* wvT_it= (u16*)alloc((size_t)768 * 768 * 2);
    u16* wc_it = (u16*)alloc((size_t)768 * 768 * 2);
    u16* wo_ti = (u16*)alloc((size_t)768 * 768 * 2);
    u16* wvT_ti= (u16*)alloc((size_t)768 * 768 * 2);
    u16* wc_ti = (u16*)alloc((size_t)768 * 768 * 2);
    u16* w1i   = (u16*)alloc((size_t)3072 * 768 * 2);
    u16* w2i   = (u16*)alloc((size_t)768 * 3072 * 2);
    u16* w1t   = (u16*)alloc((size_t)3072 * 768 * 2);
    u16* w2t   = (u16*)alloc((size_t)768 * 3072 * 2);
    u16* wp    = (u16*)alloc((size_t)768 * 1536 * 2);
    float* bc_it = (float*)alloc(768 * 4);
    float* bc_ti = (float*)alloc(768 * 4);
    // activations
    u16* vbuf  = (u16*)alloc((size_t)BROWS * 768 * 2);   // post-LN bf16
    u16* fused = (u16*)alloc((size_t)BROWS * 1536 * 2);  // [img | txt] bf16
    u16* text_bf = fused;     // alias: text_bf dead before fused is written
    // hbuf (FFN hidden, adaptive chunk) and pbuf (bf16 pre-LN) share a region.
    int fch = 16384;
    while (fch > 2048 && off + (size_t)fch * 3072 * 2 > ws_size) fch >>= 1;
    size_t region = (size_t)fch * 3072 * 2;
    if (region < (size_t)BROWS * 768 * 2) region = (size_t)BROWS * 768 * 2;
    u16* hbuf = (u16*)alloc(region);
    u16* pbuf = hbuf;

    auto gemm = [&](const u16* A, int lda, const u16* W, int M, int N, int K,
                    const float* bias, const float* R, int ldr,
                    const u16* Rb, int ldrb,
                    float* Cf, int ldcf, u16* Cb, int ldcb, int dg) {
        gemm_bt<<<dim3(N / 256, M / 256), dim3(512), 0, stream>>>(
            A, lda, W, bias, R, ldr, Rb, ldrb, Cf, ldcf, Cb, ldcb, K, dg);
    };
    auto ffn = [&](const u16* xin, const u16* W1, const float* b1,
                   const u16* W2, const float* b2, u16* outp, int ldout) {
        for (int c = 0; c < BROWS / fch; c++) {
            const u16* xc = xin + (size_t)c * fch * 768;
            gemm(xc, 768, W1, fch, 3072, 768, b1,
                 nullptr, 0, nullptr, 0, nullptr, 0, hbuf, 3072, 1);
            gemm(hbuf, 3072, W2, fch, 768, 3072, b2,
                 nullptr, 0, xc, 768,
                 nullptr, 0, outp + (size_t)c * fch * ldout, ldout, 0);
        }
    };

    // ---- conversions: one batched dispatch ----
    ConvBatch cbt = { fi_W1, fi_W2, ft_W1, ft_W2, fp_W, it_Wo, ti_Wo, text,
                      w1i,   w2i,   w1t,   w2t,   wp,   wo_it, wo_ti, text_bf };
    conv8_k<<<dim3(CONV_BLOCKS), dim3(256), 0, stream>>>(cbt);
    // ---- weight combine: Wc = Wo@Wv (bf16), bc = Wo@bv + bo ----
    f32_to_bf16_T_k<<<dim3(24, 24), dim3(256), 0, stream>>>(it_Wv, wvT_it, 768, 768);
    gemm(wo_it, 768, wvT_it, 768, 768, 768, nullptr,
         nullptr, 0, nullptr, 0, nullptr, 0, wc_it, 768, 0);
    bias_comb_k<<<dim3(192), dim3(256), 0, stream>>>(it_Wo, it_bv, it_bo, bc_it, 768);
    f32_to_bf16_T_k<<<dim3(24, 24), dim3(256), 0, stream>>>(ti_Wv, wvT_ti, 768, 768);
    gemm(wo_ti, 768, wvT_ti, 768, 768, 768, nullptr,
         nullptr, 0, nullptr, 0, nullptr, 0, wc_ti, 768, 0);
    bias_comb_k<<<dim3(192), dim3(256), 0, stream>>>(ti_Wo, ti_bv, ti_bo, bc_ti, 768);

    // ---- image path: att = text@Wc.T + bc + image ; LN1 ----
    gemm(text_bf, 768, wc_it, BROWS, 768, 768, bc_it,
         image, 768, nullptr, 0, nullptr, 0, pbuf, 768, 0);
    ln_k<<<dim3(BROWS), dim3(256), 0, stream>>>(
        pbuf, nullptr, ln_img_g, ln_img_b, nullptr, vbuf, 0);
    ffn(vbuf, w1i, fi_b1, w2i, fi_b2, fused, 1536);   // -> fused[:, :768]
    // ---- text path: kv = post-FFN img (fused left half) ----
    gemm(fused, 1536, wc_ti, BROWS, 768, 768, bc_ti,
         text, 768, nullptr, 0, nullptr, 0, pbuf, 768, 0);
    ln_k<<<dim3(BROWS), dim3(256), 0, stream>>>(
        pbuf, nullptr, ln_txt_g, ln_txt_b, nullptr, vbuf, 0);
    ffn(vbuf, w1t, ft_b1, w2t, ft_b2, fused + 768, 1536);  // -> fused[:, 768:]
    // ---- final projection + LN + gelu ----
    gemm(fused, 1536, wp, BROWS, 768, 1536, fp_b,
         nullptr, 0, nullptr, 0, nullptr, 0, pbuf, 768, 0);
    ln_k<<<dim3(BROWS), dim3(256), 0, stream>>>(
        pbuf, nullptr, fp_ln_g, fp_ln_b, (float*)d_out, nullptr, 1);
}

// Round 3
// 1093.543 us; speedup vs baseline: 1.2182x; 1.0350x over previous
//
#include <hip/hip_runtime.h>
#include <hip/hip_bf16.h>
#include <math.h>

// CrossAttentionFusion on MI355X.
// softmax over one key == 1  =>  mha1(q_in, kv) = kv@Wc.T + bc,
//   Wc = Wo@Wv (fused once), bc = Wo@bv + bo.
// 2 tiny weight-combine GEMMs + 7 bf16-MFMA GEMMs + 3 layernorms.
// R8: hot-loop LDS reads converted to inline-asm ds_read_b128 (+ explicit
// lgkmcnt(0) + sched_barrier fence, rule-18). R7 measured 1725 cy/phase vs
// ~400 ideal: the compiler-visible ds_reads of sA/sB alias the outstanding
// global_load_lds stream, so the backend inserted its own s_waitcnt vmcnt(0)
// before every phase's read cluster (our asm vmcnt(4) is opaque to its
// bookkeeping), re-draining the prefetch pipeline each phase. With asm reads
// the waitcnt pass has nothing to protect; our counted vmcnt governs alone.
// Schedule/slots/swizzle identical to R7 (verified): K-tile=64, 2 tiles/iter,
// 8 phases, 4 k-half slots x 16KB per tensor (128 KiB), vmcnt(4) twice/iter.

typedef unsigned short u16;
typedef __bf16 bf16_t;
typedef bf16_t bf16x8 __attribute__((ext_vector_type(8)));
typedef float f32x4 __attribute__((ext_vector_type(4)));

#define BROWS 16384   // batch
#define EDIM  768

__device__ __forceinline__ u16 f2bf(float f) {
    union { float f; unsigned u; } v; v.f = f;
    return (u16)((v.u + 0x7FFFu + ((v.u >> 16) & 1u)) >> 16);  // RNE
}
__device__ __forceinline__ float bf2f(u16 h) {
    union { unsigned u; float f; } v; v.u = ((unsigned)h) << 16;
    return v.f;
}
// gelu via x*sigmoid(1.5957691*x + 0.0713548*x^3); exp2/rcp HW instrs.
__device__ __forceinline__ float gelu_f(float x) {
    float t = x * x;
    float p = fmaf(0.102943268f, t, 2.30221895f);   // log2(e) folded in
    float e = __builtin_amdgcn_exp2f(-x * p);
    return x * __builtin_amdgcn_rcpf(1.0f + e);
}

// async global->LDS, 16B/lane. LDS dest is wave-uniform base + lane*16.
__device__ __forceinline__ void gld16(const u16* g, u16* l) {
    __builtin_amdgcn_global_load_lds(
        (__attribute__((address_space(1))) void*)g,
        (__attribute__((address_space(3))) void*)l, 16, 0, 0);
}

// ---- batched f32->bf16 conversion: 8 tensors, one dispatch ----
struct ConvBatch {
    const float *s0, *s1, *s2, *s3, *s4, *s5, *s6, *s7;
    u16 *d0, *d1, *d2, *d3, *d4, *d5, *d6, *d7;
};
#define CB0 2304   // fi_W1 3072*768
#define CB1 2304   // fi_W2
#define CB2 2304   // ft_W1
#define CB3 2304   // ft_W2
#define CB4 1152   // fp_W 768*1536
#define CB5 576    // it_Wo 768*768
#define CB6 576    // ti_Wo
#define CB7 12288  // text 16384*768
#define CONV_BLOCKS (CB0+CB1+CB2+CB3+CB4+CB5+CB6+CB7)

__global__ void __launch_bounds__(256) conv8_k(ConvBatch cb) {
    int b = blockIdx.x;
    const float* s; u16* d;
    if      (b < CB0)          { s = cb.s0; d = cb.d0; }
    else if ((b -= CB0) < CB1) { s = cb.s1; d = cb.d1; }
    else if ((b -= CB1) < CB2) { s = cb.s2; d = cb.d2; }
    else if ((b -= CB2) < CB3) { s = cb.s3; d = cb.d3; }
    else if ((b -= CB3) < CB4) { s = cb.s4; d = cb.d4; }
    else if ((b -= CB4) < CB5) { s = cb.s5; d = cb.d5; }
    else if ((b -= CB5) < CB6) { s = cb.s6; d = cb.d6; }
    else    { b -= CB6;          s = cb.s7; d = cb.d7; }
    int i = b * 256 + threadIdx.x;
    float4 v = ((const float4*)s)[i];
    ushort4 o;
    o.x = f2bf(v.x); o.y = f2bf(v.y); o.z = f2bf(v.z); o.w = f2bf(v.w);
    ((ushort4*)d)[i] = o;
}

// D[c,r] = bf16(S[r,c]) — transpose-convert (Wv.T for the weight combine).
__global__ void __launch_bounds__(256) f32_to_bf16_T_k(const float* __restrict__ S,
                                                       u16* __restrict__ D,
                                                       int R, int C) {
    __shared__ float t[32][33];
    const int r0 = blockIdx.y * 32, c0 = blockIdx.x * 32;
    const int tx = threadIdx.x & 31, ty = threadIdx.x >> 5;  // ty 0..7
#pragma unroll
    for (int i = ty; i < 32; i += 8) t[i][tx] = S[(long)(r0 + i) * C + c0 + tx];
    __syncthreads();
#pragma unroll
    for (int i = ty; i < 32; i += 8) D[(long)(c0 + i) * R + r0 + tx] = f2bf(t[tx][i]);
}

// bc[n] = bo[n] + dot(Wo[n,:], bv)
__global__ void __launch_bounds__(256) bias_comb_k(const float* __restrict__ Wo,
                                                   const float* __restrict__ bv,
                                                   const float* __restrict__ bo,
                                                   float* __restrict__ bc, int K) {
    const int n = blockIdx.x * 4 + (threadIdx.x >> 6);
    const int lane = threadIdx.x & 63;
    float s = 0.f;
    for (int k = lane; k < K; k += 64) s += Wo[(long)n * K + k] * bv[k];
#pragma unroll
    for (int o = 32; o > 0; o >>= 1) s += __shfl_down(s, o, 64);
    if (lane == 0) bc[n] = s + bo[n];
}

// C[m,n] = sum_k A[m,k] * W[n,k]  (+bias, +f32 or bf16 residual, opt gelu)
// 256x256 tile, 8 waves (2M x 4N), per-wave C = 128x64. 8-phase pipeline.
__global__ void __launch_bounds__(512, 2) gemm_bt(
    const u16* __restrict__ A, int lda,
    const u16* __restrict__ W,
    const float* __restrict__ bias,
    const float* __restrict__ R, int ldr,      // f32 residual (or null)
    const u16* __restrict__ Rb, int ldrb,      // bf16 residual (or null)
    float* __restrict__ Cf, int ldcf,
    u16* __restrict__ Cb, int ldcb,
    int K, int do_gelu)
{
    // 4 slots per tensor, each = one k-half: 256 rows x 32 k = 16 KB.
    // Tile t: ks-half -> slot (2t+ks)&3. Even tile -> slots 0/1, odd -> 2/3.
    __shared__ alignas(16) u16 sA[4][256 * 32];
    __shared__ alignas(16) u16 sB[4][256 * 32];

    const int tid  = threadIdx.x;
    const int lane = tid & 63;
    const int wave = tid >> 6;     // 0..7
    const int wm = wave >> 2;      // 0..1  (M half)
    const int wn = wave & 3;       // 0..3  (N quarter)

    // XCD-aware swizzle: id%8 = XCD (round-robin dispatch). Give each XCD a
    // contiguous slab of row-tiles; sweep col-tiles fastest within the slab.
    int bm, bn;
    {
        const int gx = gridDim.x, gy = gridDim.y;
        const int id = blockIdx.y * gx + blockIdx.x;
        if ((gy & 7) == 0) {
            const int xcd = id & 7, slot = id >> 3;
            bn = slot % gx;
            bm = (xcd * (gy >> 3)) + slot / gx;
        } else { bm = blockIdx.y; bn = blockIdx.x; }
    }
    const long m0 = (long)bm * 256;
    const long n0 = (long)bn * 256;

    // Staging: one 16KB half per phase = 2 rounds x (512 thr x 16B).
    // Lane l of wave w covers LDS row (rd*128 + w*16 + (l>>2)), 16B-block
    // (l&3); LDS offset = rd*8192 + w*1024 + l*16 (linear per wave, DMA-ok).
    // Bank swizzle: LDS block b of row r holds global k-block b^((r>>1)&3)
    // -> source k-block = (l&3) ^ ((l>>3)&3). Reads un-XOR it.
    const int srow = lane >> 2;                          // 0..15
    const int sk   = ((lane & 3) ^ ((lane >> 3) & 3)) * 8;
    const u16* gA = A + (m0 + wave * 16 + srow) * (long)lda + sk;
    const u16* gB = W + (n0 + wave * 16 + srow) * (long)K + sk;
    const long rdA2 = 128 * (long)lda;
    const long rdB2 = 128 * (long)K;

#define STA(sl, t, ks) do { const u16* g_ = gA + (t) * 64 + (ks) * 32; \
    gld16(g_,        &sA[sl][wave * 512]); \
    gld16(g_ + rdA2, &sA[sl][4096 + wave * 512]); } while (0)
#define STB(sl, t, ks) do { const u16* g_ = gB + (t) * 64 + (ks) * 32; \
    gld16(g_,        &sB[sl][wave * 512]); \
    gld16(g_ + rdB2, &sB[sl][4096 + wave * 512]); } while (0)

    const int quad = lane >> 4;    // 0..3 -> k = quad*8 + j
    const int l16  = lane & 15;    // m (A) / n (B) index within fragment
    const int koff = (quad ^ ((l16 >> 1) & 3)) << 4;     // un-swizzled 16B blk
    // 32-bit LDS base addresses for asm ds_read (AS3 pointers are 32-bit).
    __attribute__((address_space(3))) const u16* baseA3 =
        (__attribute__((address_space(3))) const u16*)
        ((const char*)&sA[0][0] + wm * 8192 + l16 * 64 + koff);
    __attribute__((address_space(3))) const u16* baseB3 =
        (__attribute__((address_space(3))) const u16*)
        ((const char*)&sB[0][0] + wn * 4096 + l16 * 64 + koff);

    f32x4 acc[8][4];
#pragma unroll
    for (int i = 0; i < 8; i++)
#pragma unroll
        for (int j = 0; j < 4; j++) {
            f32x4 z = {0.f, 0.f, 0.f, 0.f};
            acc[i][j] = z;
        }
    bf16x8 af0, af1, af2, af3, bf0, bf1, bf2, bf3;

// asm ds_read: invisible to the backend's waitcnt pass (the whole point).
#define DSR(dst, base, off) \
    asm volatile("ds_read_b128 %0, %1 offset:%2" \
                 : "=v"(dst) : "v"(base), "i"(off))
#define VM4   asm volatile("s_waitcnt vmcnt(4)" ::: "memory")
#define NOWAIT ((void)0)

    // Phase: 4 asm ds_read (A quadrant) [+4 (B k-half)], issue one half-tile
    // stage, optional counted vmcnt, barrier, lgkmcnt(0)+sched fence
    // (rule 18: asm reads are untracked), 16 MFMA @prio1, barrier.
#define PHASE(SLA, MQ, LB, SLB, STG, WAIT) do {                              \
    DSR(af0, baseA3, (SLA) * 16384 + (MQ) * 4096 + 0);                       \
    DSR(af1, baseA3, (SLA) * 16384 + (MQ) * 4096 + 1024);                    \
    DSR(af2, baseA3, (SLA) * 16384 + (MQ) * 4096 + 2048);                    \
    DSR(af3, baseA3, (SLA) * 16384 + (MQ) * 4096 + 3072);                    \
    if (LB) {                                                                \
        DSR(bf0, baseB3, (SLB) * 16384 + 0);                                 \
        DSR(bf1, baseB3, (SLB) * 16384 + 1024);                              \
        DSR(bf2, baseB3, (SLB) * 16384 + 2048);                              \
        DSR(bf3, baseB3, (SLB) * 16384 + 3072);                              \
    }                                                                        \
    STG;                                                                     \
    WAIT;                                                                    \
    __builtin_amdgcn_sched_barrier(0);                                       \
    __builtin_amdgcn_s_barrier();                                            \
    asm volatile("s_waitcnt lgkmcnt(0)" ::: "memory");                       \
    __builtin_amdgcn_sched_barrier(0);                                       \
    __builtin_amdgcn_s_setprio(1);                                           \
    acc[(MQ)*4+0][0] = __builtin_amdgcn_mfma_f32_16x16x32_bf16(af0, bf0, acc[(MQ)*4+0][0], 0, 0, 0); \
    acc[(MQ)*4+0][1] = __builtin_amdgcn_mfma_f32_16x16x32_bf16(af0, bf1, acc[(MQ)*4+0][1], 0, 0, 0); \
    acc[(MQ)*4+0][2] = __builtin_amdgcn_mfma_f32_16x16x32_bf16(af0, bf2, acc[(MQ)*4+0][2], 0, 0, 0); \
    acc[(MQ)*4+0][3] = __builtin_amdgcn_mfma_f32_16x16x32_bf16(af0, bf3, acc[(MQ)*4+0][3], 0, 0, 0); \
    acc[(MQ)*4+1][0] = __builtin_amdgcn_mfma_f32_16x16x32_bf16(af1, bf0, acc[(MQ)*4+1][0], 0, 0, 0); \
    acc[(MQ)*4+1][1] = __builtin_amdgcn_mfma_f32_16x16x32_bf16(af1, bf1, acc[(MQ)*4+1][1], 0, 0, 0); \
    acc[(MQ)*4+1][2] = __builtin_amdgcn_mfma_f32_16x16x32_bf16(af1, bf2, acc[(MQ)*4+1][2], 0, 0, 0); \
    acc[(MQ)*4+1][3] = __builtin_amdgcn_mfma_f32_16x16x32_bf16(af1, bf3, acc[(MQ)*4+1][3], 0, 0, 0); \
    acc[(MQ)*4+2][0] = __builtin_amdgcn_mfma_f32_16x16x32_bf16(af2, bf0, acc[(MQ)*4+2][0], 0, 0, 0); \
    acc[(MQ)*4+2][1] = __builtin_amdgcn_mfma_f32_16x16x32_bf16(af2, bf1, acc[(MQ)*4+2][1], 0, 0, 0); \
    acc[(MQ)*4+2][2] = __builtin_amdgcn_mfma_f32_16x16x32_bf16(af2, bf2, acc[(MQ)*4+2][2], 0, 0, 0); \
    acc[(MQ)*4+2][3] = __builtin_amdgcn_mfma_f32_16x16x32_bf16(af2, bf3, acc[(MQ)*4+2][3], 0, 0, 0); \
    acc[(MQ)*4+3][0] = __builtin_amdgcn_mfma_f32_16x16x32_bf16(af3, bf0, acc[(MQ)*4+3][0], 0, 0, 0); \
    acc[(MQ)*4+3][1] = __builtin_amdgcn_mfma_f32_16x16x32_bf16(af3, bf1, acc[(MQ)*4+3][1], 0, 0, 0); \
    acc[(MQ)*4+3][2] = __builtin_amdgcn_mfma_f32_16x16x32_bf16(af3, bf2, acc[(MQ)*4+3][2], 0, 0, 0); \
    acc[(MQ)*4+3][3] = __builtin_amdgcn_mfma_f32_16x16x32_bf16(af3, bf3, acc[(MQ)*4+3][3], 0, 0, 0); \
    __builtin_amdgcn_s_setprio(0);                                           \
    __builtin_amdgcn_sched_barrier(0);                                       \
    __builtin_amdgcn_s_barrier();                                            \
  } while (0)

    const int nt = K >> 6;         // 64-wide K-tiles; all K here: nt even >= 12
    // Prologue: tile0 fully + tile1 ks0 (6 halves, 12 loads); land tile0.
    STA(0, 0, 0); STB(0, 0, 0);
    STA(1, 0, 1); STB(1, 0, 1);
    STA(2, 1, 0); STB(2, 1, 0);
    VM4;                           // tile0's 8 loads landed, 4 in flight
    __builtin_amdgcn_s_barrier();

    for (int T = 0; T < nt; T += 2) {
        const int t2 = (T + 2 < nt) ? T + 2 : 0;   // tail: wrap-stage (never
        const int t3 = (T + 3 < nt) ? T + 3 : 1;   // read; keeps vmcnt uniform)
        PHASE(0, 0, 1, 0, STA(3, T + 1, 1), NOWAIT);   // tile T  ks0, mq0
        PHASE(0, 1, 0, 0, STB(3, T + 1, 1), VM4);      // tile T  ks0, mq1
        PHASE(1, 0, 1, 1, STA(0, t2, 0),    NOWAIT);   // tile T  ks1, mq0
        PHASE(1, 1, 0, 1, STB(0, t2, 0),    NOWAIT);   // tile T  ks1, mq1
        PHASE(2, 0, 1, 2, STA(1, t2, 1),    NOWAIT);   // tile T+1 ks0, mq0
        PHASE(2, 1, 0, 2, STB(1, t2, 1),    VM4);      // tile T+1 ks0, mq1
        PHASE(3, 0, 1, 3, STA(2, t3, 0),    NOWAIT);   // tile T+1 ks1, mq0
        PHASE(3, 1, 0, 3, STB(2, t3, 0),    NOWAIT);   // tile T+1 ks1, mq1
    }

    // epilogue: C/D layout col = lane&15, row = quad*4 + reg  [m89/m91]
#pragma unroll
    for (int mt = 0; mt < 8; mt++) {
#pragma unroll
        for (int nf = 0; nf < 4; nf++) {
            const long col = n0 + wn * 64 + nf * 16 + l16;
            const float bv = bias ? bias[col] : 0.0f;
#pragma unroll
            for (int rr = 0; rr < 4; rr++) {
                const long row = m0 + wm * 128 + mt * 16 + quad * 4 + rr;
                float v = acc[mt][nf][rr] + bv;
                if (R)  v += R[row * (long)ldr + col];
                if (Rb) v += bf2f(Rb[row * (long)ldrb + col]);
                if (do_gelu) v = gelu_f(v);
                if (Cf) Cf[row * (long)ldcf + col] = v;
                if (Cb) Cb[row * (long)ldcb + col] = f2bf(v);
            }
        }
    }
#undef PHASE
#undef DSR
#undef STA
#undef STB
#undef VM4
#undef NOWAIT
}

// LayerNorm over 768 cols, one block/row. Input bf16 (Xb) or f32 (Xf);
// output f32 (Yf) and/or bf16 (Yb); optional gelu. 192 active lanes x 4 elems.
__global__ void __launch_bounds__(256) ln_k(
    const u16*  __restrict__ Xb,
    const float* __restrict__ Xf,
    const float* __restrict__ g,
    const float* __restrict__ b,
    float* __restrict__ Yf,
    u16*   __restrict__ Yb,
    int do_gelu)
{
    const int row = blockIdx.x;
    const int tid = threadIdx.x;
    float v[4] = {0.f, 0.f, 0.f, 0.f};
    if (tid < 192) {
        if (Xb) {
            ushort4 u = ((const ushort4*)(Xb + (long)row * EDIM))[tid];
            v[0] = bf2f(u.x); v[1] = bf2f(u.y); v[2] = bf2f(u.z); v[3] = bf2f(u.w);
        } else {
            float4 f = ((const float4*)(Xf + (long)row * EDIM))[tid];
            v[0] = f.x; v[1] = f.y; v[2] = f.z; v[3] = f.w;
        }
    }
    float s = 0.f, s2 = 0.f;
#pragma unroll
    for (int j = 0; j < 4; j++) { s += v[j]; s2 += v[j] * v[j]; }
#pragma unroll
    for (int o = 32; o > 0; o >>= 1) {
        s  += __shfl_down(s,  o, 64);
        s2 += __shfl_down(s2, o, 64);
    }
    __shared__ float red[8];
    __shared__ float mb[2];
    const int wave = tid >> 6, lane = tid & 63;
    if (lane == 0) { red[wave] = s; red[4 + wave] = s2; }
    __syncthreads();
    if (tid == 0) {
        float S  = red[0] + red[1] + red[2] + red[3];
        float S2 = red[4] + red[5] + red[6] + red[7];
        float mean = S * (1.0f / 768.0f);
        float var  = S2 * (1.0f / 768.0f) - mean * mean;
        mb[0] = mean;
        mb[1] = rsqrtf(var + 1e-5f);
    }
    __syncthreads();
    if (tid < 192) {
        const float mean = mb[0], inv = mb[1];
        float y[4];
#pragma unroll
        for (int j = 0; j < 4; j++) {
            const int c = tid * 4 + j;
            y[j] = (v[j] - mean) * inv * g[c] + b[c];
            if (do_gelu) y[j] = gelu_f(y[j]);
        }
        if (Yf) {
            float4 o = {y[0], y[1], y[2], y[3]};
            ((float4*)(Yf + (long)row * EDIM))[tid] = o;
        }
        if (Yb) {
            ushort4 o = {f2bf(y[0]), f2bf(y[1]), f2bf(y[2]), f2bf(y[3])};
            ((ushort4*)(Yb + (long)row * EDIM))[tid] = o;
        }
    }
}

extern "C" void kernel_launch(void* const* d_in, const int* in_sizes, int n_in,
                              void* d_out, int out_size, void* d_ws, size_t ws_size,
                              hipStream_t stream) {
    (void)in_sizes; (void)n_in; (void)out_size;
    const float* image    = (const float*)d_in[0];
    const float* text     = (const float*)d_in[1];
    const float* it_Wv    = (const float*)d_in[4];
    const float* it_Wo    = (const float*)d_in[5];
    const float* it_bv    = (const float*)d_in[8];
    const float* it_bo    = (const float*)d_in[9];
    const float* ti_Wv    = (const float*)d_in[12];
    const float* ti_Wo    = (const float*)d_in[13];
    const float* ti_bv    = (const float*)d_in[16];
    const float* ti_bo    = (const float*)d_in[17];
    const float* ln_img_g = (const float*)d_in[18];
    const float* ln_img_b = (const float*)d_in[19];
    const float* ln_txt_g = (const float*)d_in[20];
    const float* ln_txt_b = (const float*)d_in[21];
    const float* fp_ln_g  = (const float*)d_in[22];
    const float* fp_ln_b  = (const float*)d_in[23];
    const float* fi_W1    = (const float*)d_in[24];
    const float* fi_b1    = (const float*)d_in[25];
    const float* fi_W2    = (const float*)d_in[26];
    const float* fi_b2    = (const float*)d_in[27];
    const float* ft_W1    = (const float*)d_in[28];
    const float* ft_b1    = (const float*)d_in[29];
    const float* ft_W2    = (const float*)d_in[30];
    const float* ft_b2    = (const float*)d_in[31];
    const float* fp_W     = (const float*)d_in[32];
    const float* fp_b     = (const float*)d_in[33];

    char* ws = (char*)d_ws;
    size_t off = 0;
    auto alloc = [&](size_t bytes) {
        char* p = ws + off; off += (bytes + 255) & ~(size_t)255; return p;
    };
    // bf16 weights (~28 MB, live whole call)
    u16* wo_it = (u16*)alloc((size_t)768 * 768 * 2);
    u16* wvT_it= (u16*)alloc((size_t)768 * 768 * 2);
    u16* wc_it = (u16*)alloc((size_t)768 * 768 * 2);
    u16* wo_ti = (u16*)alloc((size_t)768 * 768 * 2);
    u16* wvT_ti= (u16*)alloc((size_t)768 * 768 * 2);
    u16* wc_ti = (u16*)alloc((size_t)768 * 768 * 2);
    u16* w1i   = (u16*)alloc((size_t)3072 * 768 * 2);
    u16* w2i   = (u16*)alloc((size_t)768 * 3072 * 2);
    u16* w1t   = (u16*)alloc((size_t)3072 * 768 * 2);
    u16* w2t   = (u16*)alloc((size_t)768 * 3072 * 2);
    u16* wp    = (u16*)alloc((size_t)768 * 1536 * 2);
    float* bc_it = (float*)alloc(768 * 4);
    float* bc_ti = (float*)alloc(768 * 4);
    // activations
    u16* vbuf  = (u16*)alloc((size_t)BROWS * 768 * 2);   // post-LN bf16
    u16* fused = (u16*)alloc((size_t)BROWS * 1536 * 2);  // [img | txt] bf16
    u16* text_bf = fused;     // alias: text_bf dead before fused is written
    // hbuf (FFN hidden, adaptive chunk) and pbuf (bf16 pre-LN) share a region.
    int fch = 16384;
    while (fch > 2048 && off + (size_t)fch * 3072 * 2 > ws_size) fch >>= 1;
    size_t region = (size_t)fch * 3072 * 2;
    if (region < (size_t)BROWS * 768 * 2) region = (size_t)BROWS * 768 * 2;
    u16* hbuf = (u16*)alloc(region);
    u16* pbuf = hbuf;

    auto gemm = [&](const u16* A, int lda, const u16* W, int M, int N, int K,
                    const float* bias, const float* R, int ldr,
                    const u16* Rb, int ldrb,
                    float* Cf, int ldcf, u16* Cb, int ldcb, int dg) {
        gemm_bt<<<dim3(N / 256, M / 256), dim3(512), 0, stream>>>(
            A, lda, W, bias, R, ldr, Rb, ldrb, Cf, ldcf, Cb, ldcb, K, dg);
    };
    auto ffn = [&](const u16* xin, const u16* W1, const float* b1,
                   const u16* W2, const float* b2, u16* outp, int ldout) {
        for (int c = 0; c < BROWS / fch; c++) {
            const u16* xc = xin + (size_t)c * fch * 768;
            gemm(xc, 768, W1, fch, 3072, 768, b1,
                 nullptr, 0, nullptr, 0, nullptr, 0, hbuf, 3072, 1);
            gemm(hbuf, 3072, W2, fch, 768, 3072, b2,
                 nullptr, 0, xc, 768,
                 nullptr, 0, outp + (size_t)c * fch * ldout, ldout, 0);
        }
    };

    // ---- conversions: one batched dispatch ----
    ConvBatch cbt = { fi_W1, fi_W2, ft_W1, ft_W2, fp_W, it_Wo, ti_Wo, text,
                      w1i,   w2i,   w1t,   w2t,   wp,   wo_it, wo_ti, text_bf };
    conv8_k<<<dim3(CONV_BLOCKS), dim3(256), 0, stream>>>(cbt);
    // ---- weight combine: Wc = Wo@Wv (bf16), bc = Wo@bv + bo ----
    f32_to_bf16_T_k<<<dim3(24, 24), dim3(256), 0, stream>>>(it_Wv, wvT_it, 768, 768);
    gemm(wo_it, 768, wvT_it, 768, 768, 768, nullptr,
         nullptr, 0, nullptr, 0, nullptr, 0, wc_it, 768, 0);
    bias_comb_k<<<dim3(192), dim3(256), 0, stream>>>(it_Wo, it_bv, it_bo, bc_it, 768);
    f32_to_bf16_T_k<<<dim3(24, 24), dim3(256), 0, stream>>>(ti_Wv, wvT_ti, 768, 768);
    gemm(wo_ti, 768, wvT_ti, 768, 768, 768, nullptr,
         nullptr, 0, nullptr, 0, nullptr, 0, wc_ti, 768, 0);
    bias_comb_k<<<dim3(192), dim3(256), 0, stream>>>(ti_Wo, ti_bv, ti_bo, bc_ti, 768);

    // ---- image path: att = text@Wc.T + bc + image ; LN1 ----
    gemm(text_bf, 768, wc_it, BROWS, 768, 768, bc_it,
         image, 768, nullptr, 0, nullptr, 0, pbuf, 768, 0);
    ln_k<<<dim3(BROWS), dim3(256), 0, stream>>>(
        pbuf, nullptr, ln_img_g, ln_img_b, nullptr, vbuf, 0);
    ffn(vbuf, w1i, fi_b1, w2i, fi_b2, fused, 1536);   // -> fused[:, :768]
    // ---- text path: kv = post-FFN img (fused left half) ----
    gemm(fused, 1536, wc_ti, BROWS, 768, 768, bc_ti,
         text, 768, nullptr, 0, nullptr, 0, pbuf, 768, 0);
    ln_k<<<dim3(BROWS), dim3(256), 0, stream>>>(
        pbuf, nullptr, ln_txt_g, ln_txt_b, nullptr, vbuf, 0);
    ffn(vbuf, w1t, ft_b1, w2t, ft_b2, fused + 768, 1536);  // -> fused[:, 768:]
    // ---- final projection + LN + gelu ----
    gemm(fused, 1536, wp, BROWS, 768, 1536, fp_b,
         nullptr, 0, nullptr, 0, nullptr, 0, pbuf, 768, 0);
    ln_k<<<dim3(BROWS), dim3(256), 0, stream>>>(
        pbuf, nullptr, fp_ln_g, fp_ln_b, (float*)d_out, nullptr, 1);
}